// Round 2
// baseline (71.293 us; speedup 1.0000x reference)
//
#include <hip/hip_runtime.h>

// QLSTM collapses analytically:
//   quantum_gate(x, p)[:, h] = prod_{j<=h} cos(p_j) * cos(x_j)  for h<4, so hx
//   (wires 4..7) never affects any gate. Per (b,h):
//     f/i/o = sigmoid(C_h * m_h), g = tanh(Cg_h * m_h),
//     m_h = cumprod cos(x[t,b,0..h]), C_h = cumprod cos(params[0..h])
//     cx_t = f*cx_{t-1} + i*g ;  hx_t = o*tanh(cx_t)
//
// Time recurrence parallelized as an affine segment scan on (A,U):
//   state' = A*state + U,  compose (later)∘(earlier): A=Al*Ae, U=Al*Ue+Ul.
// One thread per (t,b) handling all 4 h. 512-thread blocks (4 batches x 128 t),
// grid=1024 -> 8192 waves = 32 waves/CU (vs 8 before). Scan = 4-step intra-wave
// shuffle scan (slots are stride-4 lanes) + 8-entry cross-wave LDS scan.

#define T_STEPS 128
#define BATCH   4096
#define NB      4     // batches per block (fast thread dim -> coalescing)
#define NT      128   // one thread per timestep
#define SLOTS_PER_WAVE 16   // 64 / NB
#define WAVES_PER_BLK  8    // NT / SLOTS_PER_WAVE

__device__ __forceinline__ float rcp_fast(float x) { return __builtin_amdgcn_rcpf(x); }
__device__ __forceinline__ float sigm(float x) { return rcp_fast(1.0f + __expf(-x)); }
__device__ __forceinline__ float tanh_fast(float x) {
    float e = __expf(2.0f * x);
    return (e - 1.0f) * rcp_fast(e + 1.0f);
}

__global__ __launch_bounds__(NB * NT, 8) void qlstm_kernel(
    const float* __restrict__ X,   // [T, B, 4]
    const float* __restrict__ pf,
    const float* __restrict__ pi,
    const float* __restrict__ pg,
    const float* __restrict__ po,
    float* __restrict__ out)       // outputs [T,B,4] ++ hx [B,4] ++ cx [B,4]
{
    const int tid   = threadIdx.x;
    const int bl    = tid & (NB - 1);          // batch-in-block 0..3
    const int t     = tid >> 2;                // timestep 0..127
    const int lane  = tid & 63;
    const int slotw = lane >> 2;               // slot-in-wave 0..15
    const int wv    = tid >> 6;                // wave-in-block 0..7
    const int b     = blockIdx.x * NB + bl;    // global batch

    // Per-gate cumulative-cos constants (wires 0..3 only; params 4..7 unused)
    float CF[4], CI[4], CG[4], CO[4];
    {
        float a = 1.f, c = 1.f, g = 1.f, o = 1.f;
#pragma unroll
        for (int j = 0; j < 4; ++j) {
            a *= __cosf(pf[j]); CF[j] = a;
            c *= __cosf(pi[j]); CI[j] = c;
            g *= __cosf(pg[j]); CG[j] = g;
            o *= __cosf(po[j]); CO[j] = o;
        }
    }

    // Load this thread's x[t,b,:] and build per-step affine (A=f, U=i*g), o.
    const float4* Xv = (const float4*)X;
    float4 xv = Xv[t * BATCH + b];
    float c0 = __cosf(xv.x);
    float c1 = __cosf(xv.y);
    float c2 = __cosf(xv.z);
    float c3 = __cosf(xv.w);
    float m0 = c0, m1 = m0 * c1, m2 = m1 * c2, m3 = m2 * c3;

    float A[4], U[4], O[4];
    {
        float mh[4] = {m0, m1, m2, m3};
#pragma unroll
        for (int h = 0; h < 4; ++h) {
            float f  = sigm(CF[h] * mh[h]);
            float ii = sigm(CI[h] * mh[h]);
            float g  = tanh_fast(CG[h] * mh[h]);
            O[h]     = sigm(CO[h] * mh[h]);
            A[h] = f;
            U[h] = ii * g;
        }
    }

    // Intra-wave inclusive scan over the 16 slots (stride-4 lanes).
    // compose self(later) with shuffled-up(earlier): U = A*pU + U; A = A*pA.
#pragma unroll
    for (int s = 1; s < SLOTS_PER_WAVE; s <<= 1) {
        const int L = s * NB;   // lane delta
        bool ok = (slotw >= s);
#pragma unroll
        for (int h = 0; h < 4; ++h) {
            float pA = __shfl_up(A[h], L);
            float pU = __shfl_up(U[h], L);
            if (ok) {
                U[h] = A[h] * pU + U[h];
                A[h] = A[h] * pA;
            }
        }
    }

    // Cross-wave scan: wave aggregates (slotw==15) -> LDS, exclusive-scan the
    // 8 waves per (b,h) column. cx0 = 0, so only exclusive U is needed back.
    __shared__ float sWA[WAVES_PER_BLK][NB][4];
    __shared__ float sWU[WAVES_PER_BLK][NB][4];
    if (slotw == SLOTS_PER_WAVE - 1) {
#pragma unroll
        for (int h = 0; h < 4; ++h) {
            sWA[wv][bl][h] = A[h];
            sWU[wv][bl][h] = U[h];
        }
    }
    __syncthreads();

    if (tid < NB * 4) {   // 16 columns, serial over 8 waves each
        const int cb = tid & (NB - 1);
        const int ch = tid >> 2;
        float acc = 0.f;
#pragma unroll
        for (int w = 0; w < WAVES_PER_BLK; ++w) {
            float a = sWA[w][cb][ch];
            float u = sWU[w][cb][ch];
            sWU[w][cb][ch] = acc;       // cx entering wave w
            acc = a * acc + u;
        }
    }
    __syncthreads();

    // cx at own t = A_incl * cx_wave_in + U_incl ; hx = o * tanh(cx)
    float4 hx, cx4;
#pragma unroll
    for (int h = 0; h < 4; ++h) {
        float cxin = sWU[wv][bl][h];            // broadcast within wave
        float cx = A[h] * cxin + U[h];
        float hxv = O[h] * tanh_fast(cx);
        (&hx.x)[h]  = hxv;
        (&cx4.x)[h] = cx;
    }

    float4* outv = (float4*)out;
    outv[t * BATCH + b] = hx;

    if (t == T_STEPS - 1) {
        outv[T_STEPS * BATCH + b] = hx;                 // final hx
        outv[T_STEPS * BATCH + BATCH + b] = cx4;        // final cx
    }
}

extern "C" void kernel_launch(void* const* d_in, const int* in_sizes, int n_in,
                              void* d_out, int out_size, void* d_ws, size_t ws_size,
                              hipStream_t stream) {
    const float* X  = (const float*)d_in[0];
    const float* pf = (const float*)d_in[1];
    const float* pi = (const float*)d_in[2];
    const float* pg = (const float*)d_in[3];
    const float* po = (const float*)d_in[4];
    float* out = (float*)d_out;

    dim3 grid(BATCH / NB);     // 1024 blocks
    dim3 block(NB * NT);       // 512 threads = 8 waves
    qlstm_kernel<<<grid, block, 0, stream>>>(X, pf, pi, pg, po, out);
}